// Round 11
// baseline (530.140 us; speedup 1.0000x reference)
//
#include <hip/hip_runtime.h>
#include <stdint.h>

#define T_SEQ   2048
#define HID     4096
#define NH      32
#define NKV     8
#define HD      128
#define QCOLS   6144
#define QK_SCALE 0.08838834764831845f  // 1/sqrt(128)

typedef _Float16 half_t;
typedef _Float16 half8 __attribute__((ext_vector_type(8)));
typedef _Float16 half4v __attribute__((ext_vector_type(4)));
typedef float    f32x4 __attribute__((ext_vector_type(4)));

typedef __attribute__((address_space(1))) const void cg_void;
typedef __attribute__((address_space(3))) void lds_void;

// ---------------- fused cast fp32 -> fp16 for all five inputs ----------------
__global__ __launch_bounds__(256) void cast_all_k(const float* __restrict__ X,
                                                  const float* __restrict__ Wq,
                                                  const float* __restrict__ Wk,
                                                  const float* __restrict__ Wv,
                                                  const float* __restrict__ Wo,
                                                  half_t* __restrict__ Xh,
                                                  half_t* __restrict__ Wqkvh,
                                                  half_t* __restrict__ Woh) {
  int i = blockIdx.x * 256 + threadIdx.x;   // float4 index, total 12582912
  const float* src; half_t* dst; int off;
  if (i < 2097152)      { src = X;  dst = Xh;               off = i; }
  else if (i < 6291456) { src = Wq; dst = Wqkvh;            off = i - 2097152; }
  else if (i < 7340032) { src = Wk; dst = Wqkvh + 16777216; off = i - 6291456; }
  else if (i < 8388608) { src = Wv; dst = Wqkvh + 20971520; off = i - 7340032; }
  else                  { src = Wo; dst = Woh;              off = i - 8388608; }
  f32x4 v = *(const f32x4*)(src + (size_t)off * 4);
  half4v o;
  o[0] = (half_t)v[0]; o[1] = (half_t)v[1]; o[2] = (half_t)v[2]; o[3] = (half_t)v[3];
  *(half4v*)(dst + (size_t)off * 4) = o;
}

// ---------------- RoPE cos/sin tables ----------------
__global__ __launch_bounds__(256) void rope_tables_k(float* __restrict__ cs) {
  int idx = blockIdx.x * 256 + threadIdx.x;  // 2048*64
  int t = idx >> 6, i = idx & 63;
  float inv = expf(-(float)i * 0.14391156831212787f);
  float a = (float)t * inv;
  cs[idx] = cosf(a);
  cs[131072 + idx] = sinf(a);
}

// ---------- fused: RoPE apply (blocks < 20480) + V transpose (rest) ----------
__global__ __launch_bounds__(256) void rope_vt_k(half_t* __restrict__ QKV,
                                                 const float* __restrict__ cs,
                                                 half_t* __restrict__ Vt) {
  if (blockIdx.x < 20480) {
    int idx = blockIdx.x * 256 + threadIdx.x;  // 2048*40*64
    int i = idx & 63;
    int rem = idx >> 6;
    int head = rem % 40;
    int t = rem / 40;
    int colbase = (head < 32) ? head * HD : HID + (head - 32) * HD;
    size_t base = (size_t)t * QCOLS + colbase;
    float c = cs[t * 64 + i], s = cs[131072 + t * 64 + i];
    float x1 = (float)QKV[base + i];
    float x2 = (float)QKV[base + 64 + i];
    float o1 = x1 * c - x2 * s;
    float o2 = x1 * s + x2 * c;
    if (head < 32) { o1 *= QK_SCALE; o2 *= QK_SCALE; }
    QKV[base + i]      = (half_t)o1;
    QKV[base + 64 + i] = (half_t)o2;
  } else {
    int idx = (blockIdx.x - 20480) * 256 + threadIdx.x;   // 8*128*256 = 262144
    int d  = idx & 127;
    int ts = (idx >> 7) & 255;
    int kh = idx >> 15;
    half8 o;
#pragma unroll
    for (int i = 0; i < 8; ++i)
      o[i] = QKV[(size_t)(ts * 8 + i) * QCOLS + HID + NKV * HD + kh * HD + d];
    *(half8*)&Vt[(size_t)kh * (HD * T_SEQ) + (size_t)d * T_SEQ + ts * 8] = o;
  }
}

// ---------------- fp16 GEMM (R3/R8-verified): 4-phase, 2-buffer, drain/tile --
template <int BM, int BN, int OUT_HALF>
__global__ __launch_bounds__(512, 2) void gemm8p_k(const half_t* __restrict__ A,
                                                   const half_t* __restrict__ Bm,
                                                   void* __restrict__ Cout,
                                                   int M, int N, int K) {
  constexpr int MF = BM / 32;   // per-wave m fragments
  constexpr int NF = BN / 64;   // per-wave n fragments
  constexpr int MH = MF / 2;    // m frags per phase
  constexpr int LA = BM / 64;   // staging loads/thread for A tile
  constexpr int LB = BN / 64;
  __shared__ half_t Al[2][BM * 64];
  __shared__ half_t Bl[2][BN * 64];

  const int nbm = M / BM;
  const int nwg = nbm * (N / BN);     // 256 for both instantiations
  const int bid = blockIdx.x;
  const int swz = (bid & 7) * (nwg >> 3) + (bid >> 3);  // bijective XCD swizzle
  const int brow = (swz % nbm) * BM;
  const int bcol = (swz / nbm) * BN;
  const int tid = threadIdx.x;
  const int lane = tid & 63, wid = tid >> 6;
  const int wr = wid >> 2, wc = wid & 3;
  const int lr = lane & 15, hi = lane >> 4;
  const int wrow = wr * (MF * 16), wcol = wc * (NF * 16);

  const half_t* Ab = A + (size_t)brow * K;
  const half_t* Bb = Bm + (size_t)bcol * K;

  f32x4 acc[MF][NF] = {};
  half8 afr[MH], bfr[NF];

#define STAGE_A(l, k0, buf) { \
    int c_ = (l) * 512 + tid; int r_ = c_ >> 3, s_ = c_ & 7; \
    __builtin_amdgcn_global_load_lds( \
      (cg_void*)(Ab + (size_t)r_ * K + (k0) + ((s_ ^ (r_ & 7)) * 8)), \
      (lds_void*)(&Al[buf][((l) * 512 + wid * 64) * 8]), 16, 0, 0); }
#define STAGE_B(l, k0, buf) { \
    int c_ = (l) * 512 + tid; int r_ = c_ >> 3, s_ = c_ & 7; \
    __builtin_amdgcn_global_load_lds( \
      (cg_void*)(Bb + (size_t)r_ * K + (k0) + ((s_ ^ (r_ & 7)) * 8)), \
      (lds_void*)(&Bl[buf][((l) * 512 + wid * 64) * 8]), 16, 0, 0); }
#define RD_A(i, mh, kk, buf) { \
    int row_ = wrow + ((mh) * MH + (i)) * 16 + lr; int ks_ = (kk) * 4 + hi; \
    afr[i] = *(const half8*)&Al[buf][row_ * 64 + ((ks_ ^ (row_ & 7)) * 8)]; }
#define RD_B(n, kk, buf) { \
    int row_ = wcol + (n) * 16 + lr; int ks_ = (kk) * 4 + hi; \
    bfr[n] = *(const half8*)&Bl[buf][row_ * 64 + ((ks_ ^ (row_ & 7)) * 8)]; }
#define MFMA_PH(mh) { \
    __builtin_amdgcn_s_setprio(1); \
    _Pragma("unroll") for (int i_ = 0; i_ < MH; ++i_) \
      _Pragma("unroll") for (int n_ = 0; n_ < NF; ++n_) \
        acc[(mh) * MH + i_][n_] = __builtin_amdgcn_mfma_f32_16x16x32_f16( \
            afr[i_], bfr[n_], acc[(mh) * MH + i_][n_], 0, 0, 0); \
    __builtin_amdgcn_s_setprio(0); }

#define DO_TILE(T, BUF) { \
    const int kn_ = ((T) + 1) * 64; const bool pf_ = ((T) + 1) < NT; \
    if (pf_) { _Pragma("unroll") for (int l_ = 0; l_ < LA; ++l_) STAGE_A(l_, kn_, (BUF) ^ 1); } \
    _Pragma("unroll") for (int n_ = 0; n_ < NF; ++n_) RD_B(n_, 0, BUF); \
    _Pragma("unroll") for (int i_ = 0; i_ < MH; ++i_) RD_A(i_, 0, 0, BUF); \
    MFMA_PH(0); \
    __builtin_amdgcn_s_barrier(); __builtin_amdgcn_sched_barrier(0); \
    if (pf_) { _Pragma("unroll") for (int l_ = 0; l_ < LB; ++l_) STAGE_B(l_, kn_, (BUF) ^ 1); } \
    _Pragma("unroll") for (int i_ = 0; i_ < MH; ++i_) RD_A(i_, 1, 0, BUF); \
    MFMA_PH(1); \
    __builtin_amdgcn_s_barrier(); __builtin_amdgcn_sched_barrier(0); \
    _Pragma("unroll") for (int n_ = 0; n_ < NF; ++n_) RD_B(n_, 1, BUF); \
    _Pragma("unroll") for (int i_ = 0; i_ < MH; ++i_) RD_A(i_, 1, 1, BUF); \
    MFMA_PH(1); \
    __builtin_amdgcn_s_barrier(); __builtin_amdgcn_sched_barrier(0); \
    _Pragma("unroll") for (int i_ = 0; i_ < MH; ++i_) RD_A(i_, 0, 1, BUF); \
    MFMA_PH(0); \
    asm volatile("s_waitcnt vmcnt(0)" ::: "memory"); \
    __syncthreads(); }

  const int NT = K / 64;
#pragma unroll
  for (int l_ = 0; l_ < LA; ++l_) STAGE_A(l_, 0, 0);
#pragma unroll
  for (int l_ = 0; l_ < LB; ++l_) STAGE_B(l_, 0, 0);
  asm volatile("s_waitcnt vmcnt(0)" ::: "memory");
  __syncthreads();

  for (int t = 0; t < NT; t += 2) {
    DO_TILE(t, 0);
    DO_TILE(t + 1, 1);
  }

#undef STAGE_A
#undef STAGE_B
#undef RD_A
#undef RD_B
#undef MFMA_PH
#undef DO_TILE

#pragma unroll
  for (int m = 0; m < MF; ++m)
#pragma unroll
    for (int n = 0; n < NF; ++n)
#pragma unroll
      for (int r = 0; r < 4; ++r) {
        int row = brow + wrow + m * 16 + hi * 4 + r;
        int col = bcol + wcol + n * 16 + lr;
        float v = acc[m][n][r];
        if (OUT_HALF) ((half_t*)Cout)[(size_t)row * N + col] = (half_t)v;
        else          ((float*)Cout)[(size_t)row * N + col] = v;
      }
}

// ---------------- fused causal GQA flash attention, 8-wave blocks ----------
// R8/R10 per-wave structure (2-phase prefetch, setprio, defer-max, lane-
// partial l) with 8 waves/block (QBLK=128, wave w owns rows qb*128+w*16).
// LDS = K dbuf 32K + V dbuf 32K + P 8x[16][64] slot-XOR 16K = 80 KB exactly
// -> 2 blocks/CU = 16 waves/CU (2x TLP vs 4-wave blocks). Grid 512: blocks
// 0-255 qb 15..8, 256-511 qb 0..7 -> per-CU pair work sums constant.
__global__ __launch_bounds__(512, 4) void attn_k(const half_t* __restrict__ QKV,
                                                 const half_t* __restrict__ Vt,
                                                 half_t* __restrict__ Ob) {
  const int bid = blockIdx.x;
  const int qb = (bid < 256) ? (15 - (bid >> 5)) : ((bid - 256) >> 5);
  const int h  = bid & 31;
  const int kh = h >> 2;
  const int tid = threadIdx.x;
  const int lane = tid & 63;
  const int w = tid >> 6;
  const int lr = lane & 15, hi = lane >> 4;
  const int qrow = qb * 128 + w * 16;

  __shared__ half_t Klds[2][64 * 128];   // [kv][128] swizzled-linear (32 KB)
  __shared__ half_t Vlds[2][128 * 64];   // [d][kv]   swizzled-linear (32 KB)
  __shared__ half_t Plds[8 * 16 * 64];   // per-wave P, slot-XOR     (16 KB)

  const half_t* Qp  = QKV + h * HD;
  const half_t* Kp  = QKV + HID + kh * HD;
  const half_t* Vtp = Vt + (size_t)kh * (HD * T_SEQ);

  half8 qf[4];
#pragma unroll
  for (int kk = 0; kk < 4; ++kk)
    qf[kk] = *(const half8*)&Qp[(size_t)(qrow + lr) * QCOLS + kk * 32 + hi * 8];

  f32x4 acc[8] = {};
  float mrow[4], lrow[4];
#pragma unroll
  for (int r = 0; r < 4; ++r) { mrow[r] = -1e30f; lrow[r] = 0.0f; }

  half_t* Pw = &Plds[w * 1024];

#define STAGE_KV(kv0, buf) { \
    _Pragma("unroll") for (int c_ = 0; c_ < 2; ++c_) { \
      int chunk_ = c_ * 512 + tid; \
      int r_ = chunk_ >> 4, s_ = chunk_ & 15; \
      int cc_ = (s_ & 8) | ((s_ ^ r_) & 7); \
      __builtin_amdgcn_global_load_lds( \
          (cg_void*)(Kp + (size_t)((kv0) + r_) * QCOLS + cc_ * 8), \
          (lds_void*)(&Klds[buf][(c_ * 512 + w * 64) * 8]), 16, 0, 0); } \
    _Pragma("unroll") for (int c_ = 0; c_ < 2; ++c_) { \
      int chunk_ = c_ * 512 + tid; \
      int r_ = chunk_ >> 3, s_ = chunk_ & 7; \
      int cc_ = (s_ ^ r_) & 7; \
      __builtin_amdgcn_global_load_lds( \
          (cg_void*)(Vtp + (size_t)r_ * T_SEQ + (kv0) + cc_ * 8), \
          (lds_void*)(&Vlds[buf][(c_ * 512 + w * 64) * 8]), 16, 0, 0); } }

#define COMPUTE(T, BUF) { \
    const int kv0_ = (T) * 64; \
    f32x4 sc[4] = {}; \
    __builtin_amdgcn_s_setprio(1); \
    _Pragma("unroll") for (int jt_ = 0; jt_ < 4; ++jt_) \
      _Pragma("unroll") for (int kk_ = 0; kk_ < 4; ++kk_) { \
        int srow_ = jt_ * 16 + lr; \
        int sl_ = kk_ * 4 + hi; \
        int c_ = (sl_ & 8) | ((sl_ ^ srow_) & 7); \
        half8 kf_ = *(const half8*)&Klds[BUF][srow_ * 128 + c_ * 8]; \
        sc[jt_] = __builtin_amdgcn_mfma_f32_16x16x32_f16(qf[kk_], kf_, sc[jt_], 0, 0, 0); \
      } \
    __builtin_amdgcn_s_setprio(0); \
    if ((T) >= 2 * qb) { \
      _Pragma("unroll") for (int jt_ = 0; jt_ < 4; ++jt_) \
        _Pragma("unroll") for (int r_ = 0; r_ < 4; ++r_) { \
          int ig_ = qrow + hi * 4 + r_; \
          int jg_ = kv0_ + jt_ * 16 + lr; \
          if (jg_ > ig_) sc[jt_][r_] = -1e30f; \
        } \
    } \
    float mx_[4]; \
    _Pragma("unroll") for (int r_ = 0; r_ < 4; ++r_) \
      mx_[r_] = fmaxf(fmaxf(sc[0][r_], sc[1][r_]), fmaxf(sc[2][r_], sc[3][r_])); \
    _Pragma("unroll") for (int off_ = 1; off_ < 16; off_ <<= 1) \
      _Pragma("unroll") for (int r_ = 0; r_ < 4; ++r_) \
        mx_[r_] = fmaxf(mx_[r_], __shfl_xor(mx_[r_], off_, 64)); \
    bool grow_ = false; \
    _Pragma("unroll") for (int r_ = 0; r_ < 4; ++r_) grow_ = grow_ || (mx_[r_] > mrow[r_]); \
    if (__any(grow_)) { \
      float scl_[4]; \
      _Pragma("unroll") for (int r_ = 0; r_ < 4; ++r_) { \
        float mn_ = fmaxf(mrow[r_], mx_[r_]); \
        scl_[r_] = __expf(mrow[r_] - mn_); \
        mrow[r_] = mn_; \
        float ls_ = 0.0f; \
        _Pragma("unroll") for (int jt_ = 0; jt_ < 4; ++jt_) { \
          sc[jt_][r_] = __expf(sc[jt_][r_] - mn_); ls_ += sc[jt_][r_]; } \
        lrow[r_] = lrow[r_] * scl_[r_] + ls_; \
      } \
      _Pragma("unroll") for (int g_ = 0; g_ < 8; ++g_) \
        _Pragma("unroll") for (int r_ = 0; r_ < 4; ++r_) acc[g_][r_] *= scl_[r_]; \
    } else { \
      _Pragma("unroll") for (int r_ = 0; r_ < 4; ++r_) { \
        float ls_ = 0.0f; \
        _Pragma("unroll") for (int jt_ = 0; jt_ < 4; ++jt_) { \
          sc[jt_][r_] = __expf(sc[jt_][r_] - mrow[r_]); ls_ += sc[jt_][r_]; } \
        lrow[r_] += ls_; \
      } \
    } \
    /* P -> fp16, slot-XOR swizzled [16][64]: slot' = slot ^ (row&7) */ \
    _Pragma("unroll") for (int jt_ = 0; jt_ < 4; ++jt_) \
      _Pragma("unroll") for (int r_ = 0; r_ < 4; ++r_) { \
        int row_ = hi * 4 + r_; \
        int slot_ = (jt_ * 2 + (lr >> 3)) ^ (row_ & 7); \
        Pw[row_ * 64 + slot_ * 8 + (lr & 7)] = (half_t)sc[jt_][r_]; \
      } \
    half8 pf0_ = *(const half8*)&Pw[lr * 64 + ((hi ^ (lr & 7)) << 3)]; \
    half8 pf1_ = *(const half8*)&Pw[lr * 64 + (((4 + hi) ^ (lr & 7)) << 3)]; \
    __builtin_amdgcn_s_setprio(1); \
    _Pragma("unroll") for (int g_ = 0; g_ < 8; ++g_) { \
      int vrow_ = g_ * 16 + lr; \
      { int c0_ = (hi ^ vrow_) & 7; \
        half8 vf_ = *(const half8*)&Vlds[BUF][vrow_ * 64 + c0_ * 8]; \
        acc[g_] = __builtin_amdgcn_mfma_f32_16x16x32_f16(pf0_, vf_, acc[g_], 0, 0, 0); } \
      { int c1_ = ((4 + hi) ^ vrow_) & 7; \
        half8 vf_ = *(const half8*)&Vlds[BUF][vrow_ * 64 + c1_ * 8]; \
        acc[g_] = __builtin_amdgcn_mfma_f32_16x16x32_f16(pf1_, vf_, acc[g_], 0, 0, 0); } \
    } \
    __builtin_amdgcn_s_setprio(0); }

#define TILE_SYNC() { asm volatile("s_waitcnt vmcnt(0)" ::: "memory"); \
                      __builtin_amdgcn_s_barrier(); __builtin_amdgcn_sched_barrier(0); }

  const int nt = 2 * qb + 2;
  STAGE_KV(0, 0);
  TILE_SYNC();

  int t = 0;
  for (; t + 2 <= nt; t += 2) {
    STAGE_KV((t + 1) * 64, 1);
    COMPUTE(t, 0);
    TILE_SYNC();
    if (t + 2 < nt) { STAGE_KV((t + 2) * 64, 0); }
    COMPUTE(t + 1, 1);
    TILE_SYNC();
  }
  if (t < nt) { COMPUTE(t, 0); }   // (nt even; kept for safety)

#undef STAGE_KV
#undef COMPUTE
#undef TILE_SYNC

  float linv[4];
#pragma unroll
  for (int r = 0; r < 4; ++r) {
    float l = lrow[r];
#pragma unroll
    for (int off = 1; off < 16; off <<= 1) l += __shfl_xor(l, off, 64);
    linv[r] = 1.0f / l;
  }
#pragma unroll
  for (int g = 0; g < 8; ++g)
#pragma unroll
    for (int r = 0; r < 4; ++r) {
      int row = qrow + hi * 4 + r;
      int col = h * HD + g * 16 + lr;
      Ob[(size_t)row * HID + col] = (half_t)(acc[g][r] * linv[r]);
    }
}

// ---------------- launch ----------------
extern "C" void kernel_launch(void* const* d_in, const int* in_sizes, int n_in,
                              void* d_out, int out_size, void* d_ws, size_t ws_size,
                              hipStream_t stream) {
  const float* hs = (const float*)d_in[0];
  const float* Wq = (const float*)d_in[1];
  const float* Wk = (const float*)d_in[2];
  const float* Wv = (const float*)d_in[3];
  const float* Wo = (const float*)d_in[4];
  float* out = (float*)d_out;

  char* ws = (char*)d_ws;
  half_t* Xh    = (half_t*)(ws + 0);           // 16 MB (dead after gemm1)
  half_t* Vt    = (half_t*)(ws + 0);           // 4 MB, reuses Xh region
  half_t* Wqkvh = (half_t*)(ws + 16777216);    // 48 MB [6144][4096]
  half_t* Woh   = (half_t*)(ws + 67108864);    // 32 MB
  half_t* QKV   = (half_t*)(ws + 100663296);   // 24 MB [2048][6144]
  half_t* attnh = (half_t*)(ws + 125829120);   // 16 MB [2048][4096]
  float*  cs    = (float*)(ws + 142606336);    // 1 MB cos|sin tables
  if (ws_size < 143654912ull) return;

  cast_all_k<<<49152, 256, 0, stream>>>(hs, Wq, Wk, Wv, Wo, Xh, Wqkvh, Woh);
  rope_tables_k<<<512, 256, 0, stream>>>(cs);

  gemm8p_k<256, 192, 1><<<256, 512, 0, stream>>>(Xh, Wqkvh, (void*)QKV, 2048, 6144, 4096);
  rope_vt_k<<<21504, 256, 0, stream>>>(QKV, cs, Vt);
  attn_k<<<512, 512, 0, stream>>>(QKV, Vt, attnh);
  gemm8p_k<128, 256, 0><<<256, 512, 0, stream>>>(attnh, Woh, (void*)out, 2048, 4096, 4096);
}

// Round 12
// 335.080 us; speedup vs baseline: 1.5821x; 1.5821x over previous
//
#include <hip/hip_runtime.h>
#include <stdint.h>

#define T_SEQ   2048
#define HID     4096
#define NH      32
#define NKV     8
#define HD      128
#define QCOLS   6144
#define QK_SCALE 0.08838834764831845f  // 1/sqrt(128)

typedef _Float16 half_t;
typedef _Float16 half8 __attribute__((ext_vector_type(8)));
typedef _Float16 half4v __attribute__((ext_vector_type(4)));
typedef float    f32x4 __attribute__((ext_vector_type(4)));

typedef __attribute__((address_space(1))) const void cg_void;
typedef __attribute__((address_space(3))) void lds_void;

// ---------------- fused cast fp32 -> fp16 for all five inputs ----------------
__global__ __launch_bounds__(256) void cast_all_k(const float* __restrict__ X,
                                                  const float* __restrict__ Wq,
                                                  const float* __restrict__ Wk,
                                                  const float* __restrict__ Wv,
                                                  const float* __restrict__ Wo,
                                                  half_t* __restrict__ Xh,
                                                  half_t* __restrict__ Wqkvh,
                                                  half_t* __restrict__ Woh) {
  int i = blockIdx.x * 256 + threadIdx.x;   // float4 index, total 12582912
  const float* src; half_t* dst; int off;
  if (i < 2097152)      { src = X;  dst = Xh;               off = i; }
  else if (i < 6291456) { src = Wq; dst = Wqkvh;            off = i - 2097152; }
  else if (i < 7340032) { src = Wk; dst = Wqkvh + 16777216; off = i - 6291456; }
  else if (i < 8388608) { src = Wv; dst = Wqkvh + 20971520; off = i - 7340032; }
  else                  { src = Wo; dst = Woh;              off = i - 8388608; }
  f32x4 v = *(const f32x4*)(src + (size_t)off * 4);
  half4v o;
  o[0] = (half_t)v[0]; o[1] = (half_t)v[1]; o[2] = (half_t)v[2]; o[3] = (half_t)v[3];
  *(half4v*)(dst + (size_t)off * 4) = o;
}

// ---------------- RoPE cos/sin tables ----------------
__global__ __launch_bounds__(256) void rope_tables_k(float* __restrict__ cs) {
  int idx = blockIdx.x * 256 + threadIdx.x;  // 2048*64
  int t = idx >> 6, i = idx & 63;
  float inv = expf(-(float)i * 0.14391156831212787f);
  float a = (float)t * inv;
  cs[idx] = cosf(a);
  cs[131072 + idx] = sinf(a);
}

// ---------- fused: RoPE apply (blocks < 20480) + V transpose (rest) ----------
__global__ __launch_bounds__(256) void rope_vt_k(half_t* __restrict__ QKV,
                                                 const float* __restrict__ cs,
                                                 half_t* __restrict__ Vt) {
  if (blockIdx.x < 20480) {
    int idx = blockIdx.x * 256 + threadIdx.x;  // 2048*40*64
    int i = idx & 63;
    int rem = idx >> 6;
    int head = rem % 40;
    int t = rem / 40;
    int colbase = (head < 32) ? head * HD : HID + (head - 32) * HD;
    size_t base = (size_t)t * QCOLS + colbase;
    float c = cs[t * 64 + i], s = cs[131072 + t * 64 + i];
    float x1 = (float)QKV[base + i];
    float x2 = (float)QKV[base + 64 + i];
    float o1 = x1 * c - x2 * s;
    float o2 = x1 * s + x2 * c;
    if (head < 32) { o1 *= QK_SCALE; o2 *= QK_SCALE; }
    QKV[base + i]      = (half_t)o1;
    QKV[base + 64 + i] = (half_t)o2;
  } else {
    int idx = (blockIdx.x - 20480) * 256 + threadIdx.x;   // 8*128*256 = 262144
    int d  = idx & 127;
    int ts = (idx >> 7) & 255;
    int kh = idx >> 15;
    half8 o;
#pragma unroll
    for (int i = 0; i < 8; ++i)
      o[i] = QKV[(size_t)(ts * 8 + i) * QCOLS + HID + NKV * HD + kh * HD + d];
    *(half8*)&Vt[(size_t)kh * (HD * T_SEQ) + (size_t)d * T_SEQ + ts * 8] = o;
  }
}

// ---------------- fp16 GEMM (R3/R8-verified): 4-phase, 2-buffer, drain/tile --
template <int BM, int BN, int OUT_HALF>
__global__ __launch_bounds__(512, 2) void gemm8p_k(const half_t* __restrict__ A,
                                                   const half_t* __restrict__ Bm,
                                                   void* __restrict__ Cout,
                                                   int M, int N, int K) {
  constexpr int MF = BM / 32;   // per-wave m fragments
  constexpr int NF = BN / 64;   // per-wave n fragments
  constexpr int MH = MF / 2;    // m frags per phase
  constexpr int LA = BM / 64;   // staging loads/thread for A tile
  constexpr int LB = BN / 64;
  __shared__ half_t Al[2][BM * 64];
  __shared__ half_t Bl[2][BN * 64];

  const int nbm = M / BM;
  const int nwg = nbm * (N / BN);     // 256 for both instantiations
  const int bid = blockIdx.x;
  const int swz = (bid & 7) * (nwg >> 3) + (bid >> 3);  // bijective XCD swizzle
  const int brow = (swz % nbm) * BM;
  const int bcol = (swz / nbm) * BN;
  const int tid = threadIdx.x;
  const int lane = tid & 63, wid = tid >> 6;
  const int wr = wid >> 2, wc = wid & 3;
  const int lr = lane & 15, hi = lane >> 4;
  const int wrow = wr * (MF * 16), wcol = wc * (NF * 16);

  const half_t* Ab = A + (size_t)brow * K;
  const half_t* Bb = Bm + (size_t)bcol * K;

  f32x4 acc[MF][NF] = {};
  half8 afr[MH], bfr[NF];

#define STAGE_A(l, k0, buf) { \
    int c_ = (l) * 512 + tid; int r_ = c_ >> 3, s_ = c_ & 7; \
    __builtin_amdgcn_global_load_lds( \
      (cg_void*)(Ab + (size_t)r_ * K + (k0) + ((s_ ^ (r_ & 7)) * 8)), \
      (lds_void*)(&Al[buf][((l) * 512 + wid * 64) * 8]), 16, 0, 0); }
#define STAGE_B(l, k0, buf) { \
    int c_ = (l) * 512 + tid; int r_ = c_ >> 3, s_ = c_ & 7; \
    __builtin_amdgcn_global_load_lds( \
      (cg_void*)(Bb + (size_t)r_ * K + (k0) + ((s_ ^ (r_ & 7)) * 8)), \
      (lds_void*)(&Bl[buf][((l) * 512 + wid * 64) * 8]), 16, 0, 0); }
#define RD_A(i, mh, kk, buf) { \
    int row_ = wrow + ((mh) * MH + (i)) * 16 + lr; int ks_ = (kk) * 4 + hi; \
    afr[i] = *(const half8*)&Al[buf][row_ * 64 + ((ks_ ^ (row_ & 7)) * 8)]; }
#define RD_B(n, kk, buf) { \
    int row_ = wcol + (n) * 16 + lr; int ks_ = (kk) * 4 + hi; \
    bfr[n] = *(const half8*)&Bl[buf][row_ * 64 + ((ks_ ^ (row_ & 7)) * 8)]; }
#define MFMA_PH(mh) { \
    __builtin_amdgcn_s_setprio(1); \
    _Pragma("unroll") for (int i_ = 0; i_ < MH; ++i_) \
      _Pragma("unroll") for (int n_ = 0; n_ < NF; ++n_) \
        acc[(mh) * MH + i_][n_] = __builtin_amdgcn_mfma_f32_16x16x32_f16( \
            afr[i_], bfr[n_], acc[(mh) * MH + i_][n_], 0, 0, 0); \
    __builtin_amdgcn_s_setprio(0); }

#define DO_TILE(T, BUF) { \
    const int kn_ = ((T) + 1) * 64; const bool pf_ = ((T) + 1) < NT; \
    if (pf_) { _Pragma("unroll") for (int l_ = 0; l_ < LA; ++l_) STAGE_A(l_, kn_, (BUF) ^ 1); } \
    _Pragma("unroll") for (int n_ = 0; n_ < NF; ++n_) RD_B(n_, 0, BUF); \
    _Pragma("unroll") for (int i_ = 0; i_ < MH; ++i_) RD_A(i_, 0, 0, BUF); \
    MFMA_PH(0); \
    __builtin_amdgcn_s_barrier(); __builtin_amdgcn_sched_barrier(0); \
    if (pf_) { _Pragma("unroll") for (int l_ = 0; l_ < LB; ++l_) STAGE_B(l_, kn_, (BUF) ^ 1); } \
    _Pragma("unroll") for (int i_ = 0; i_ < MH; ++i_) RD_A(i_, 1, 0, BUF); \
    MFMA_PH(1); \
    __builtin_amdgcn_s_barrier(); __builtin_amdgcn_sched_barrier(0); \
    _Pragma("unroll") for (int n_ = 0; n_ < NF; ++n_) RD_B(n_, 1, BUF); \
    _Pragma("unroll") for (int i_ = 0; i_ < MH; ++i_) RD_A(i_, 1, 1, BUF); \
    MFMA_PH(1); \
    __builtin_amdgcn_s_barrier(); __builtin_amdgcn_sched_barrier(0); \
    _Pragma("unroll") for (int i_ = 0; i_ < MH; ++i_) RD_A(i_, 0, 1, BUF); \
    MFMA_PH(0); \
    asm volatile("s_waitcnt vmcnt(0)" ::: "memory"); \
    __syncthreads(); }

  const int NT = K / 64;
#pragma unroll
  for (int l_ = 0; l_ < LA; ++l_) STAGE_A(l_, 0, 0);
#pragma unroll
  for (int l_ = 0; l_ < LB; ++l_) STAGE_B(l_, 0, 0);
  asm volatile("s_waitcnt vmcnt(0)" ::: "memory");
  __syncthreads();

  for (int t = 0; t < NT; t += 2) {
    DO_TILE(t, 0);
    DO_TILE(t + 1, 1);
  }

#undef STAGE_A
#undef STAGE_B
#undef RD_A
#undef RD_B
#undef MFMA_PH
#undef DO_TILE

#pragma unroll
  for (int m = 0; m < MF; ++m)
#pragma unroll
    for (int n = 0; n < NF; ++n)
#pragma unroll
      for (int r = 0; r < 4; ++r) {
        int row = brow + wrow + m * 16 + hi * 4 + r;
        int col = bcol + wcol + n * 16 + lr;
        float v = acc[m][n][r];
        if (OUT_HALF) ((half_t*)Cout)[(size_t)row * N + col] = (half_t)v;
        else          ((float*)Cout)[(size_t)row * N + col] = v;
      }
}

// ---------------- fused causal GQA flash attention, 8-wave blocks ----------
// R11 structure with the spill fixed: __launch_bounds__(512, 2) -> VGPR cap
// 256 (compiler lands ~128, as in the 4-wave variant) -> no scratch traffic.
// At 128 VGPR the HW ladder gives 16 waves/CU; LDS 80 KB x 2 = 160 KB fits
// exactly 2 blocks/CU -> intended 2x TLP without spills.
__global__ __launch_bounds__(512, 2) void attn_k(const half_t* __restrict__ QKV,
                                                 const half_t* __restrict__ Vt,
                                                 half_t* __restrict__ Ob) {
  const int bid = blockIdx.x;
  const int qb = (bid < 256) ? (15 - (bid >> 5)) : ((bid - 256) >> 5);
  const int h  = bid & 31;
  const int kh = h >> 2;
  const int tid = threadIdx.x;
  const int lane = tid & 63;
  const int w = tid >> 6;
  const int lr = lane & 15, hi = lane >> 4;
  const int qrow = qb * 128 + w * 16;

  __shared__ half_t Klds[2][64 * 128];   // [kv][128] swizzled-linear (32 KB)
  __shared__ half_t Vlds[2][128 * 64];   // [d][kv]   swizzled-linear (32 KB)
  __shared__ half_t Plds[8 * 16 * 64];   // per-wave P, slot-XOR     (16 KB)

  const half_t* Qp  = QKV + h * HD;
  const half_t* Kp  = QKV + HID + kh * HD;
  const half_t* Vtp = Vt + (size_t)kh * (HD * T_SEQ);

  half8 qf[4];
#pragma unroll
  for (int kk = 0; kk < 4; ++kk)
    qf[kk] = *(const half8*)&Qp[(size_t)(qrow + lr) * QCOLS + kk * 32 + hi * 8];

  f32x4 acc[8] = {};
  float mrow[4], lrow[4];
#pragma unroll
  for (int r = 0; r < 4; ++r) { mrow[r] = -1e30f; lrow[r] = 0.0f; }

  half_t* Pw = &Plds[w * 1024];

#define STAGE_KV(kv0, buf) { \
    _Pragma("unroll") for (int c_ = 0; c_ < 2; ++c_) { \
      int chunk_ = c_ * 512 + tid; \
      int r_ = chunk_ >> 4, s_ = chunk_ & 15; \
      int cc_ = (s_ & 8) | ((s_ ^ r_) & 7); \
      __builtin_amdgcn_global_load_lds( \
          (cg_void*)(Kp + (size_t)((kv0) + r_) * QCOLS + cc_ * 8), \
          (lds_void*)(&Klds[buf][(c_ * 512 + w * 64) * 8]), 16, 0, 0); } \
    _Pragma("unroll") for (int c_ = 0; c_ < 2; ++c_) { \
      int chunk_ = c_ * 512 + tid; \
      int r_ = chunk_ >> 3, s_ = chunk_ & 7; \
      int cc_ = (s_ ^ r_) & 7; \
      __builtin_amdgcn_global_load_lds( \
          (cg_void*)(Vtp + (size_t)r_ * T_SEQ + (kv0) + cc_ * 8), \
          (lds_void*)(&Vlds[buf][(c_ * 512 + w * 64) * 8]), 16, 0, 0); } }

#define COMPUTE(T, BUF) { \
    const int kv0_ = (T) * 64; \
    f32x4 sc[4] = {}; \
    __builtin_amdgcn_s_setprio(1); \
    _Pragma("unroll") for (int jt_ = 0; jt_ < 4; ++jt_) \
      _Pragma("unroll") for (int kk_ = 0; kk_ < 4; ++kk_) { \
        int srow_ = jt_ * 16 + lr; \
        int sl_ = kk_ * 4 + hi; \
        int c_ = (sl_ & 8) | ((sl_ ^ srow_) & 7); \
        half8 kf_ = *(const half8*)&Klds[BUF][srow_ * 128 + c_ * 8]; \
        sc[jt_] = __builtin_amdgcn_mfma_f32_16x16x32_f16(qf[kk_], kf_, sc[jt_], 0, 0, 0); \
      } \
    __builtin_amdgcn_s_setprio(0); \
    if ((T) >= 2 * qb) { \
      _Pragma("unroll") for (int jt_ = 0; jt_ < 4; ++jt_) \
        _Pragma("unroll") for (int r_ = 0; r_ < 4; ++r_) { \
          int ig_ = qrow + hi * 4 + r_; \
          int jg_ = kv0_ + jt_ * 16 + lr; \
          if (jg_ > ig_) sc[jt_][r_] = -1e30f; \
        } \
    } \
    float mx_[4]; \
    _Pragma("unroll") for (int r_ = 0; r_ < 4; ++r_) \
      mx_[r_] = fmaxf(fmaxf(sc[0][r_], sc[1][r_]), fmaxf(sc[2][r_], sc[3][r_])); \
    _Pragma("unroll") for (int off_ = 1; off_ < 16; off_ <<= 1) \
      _Pragma("unroll") for (int r_ = 0; r_ < 4; ++r_) \
        mx_[r_] = fmaxf(mx_[r_], __shfl_xor(mx_[r_], off_, 64)); \
    bool grow_ = false; \
    _Pragma("unroll") for (int r_ = 0; r_ < 4; ++r_) grow_ = grow_ || (mx_[r_] > mrow[r_]); \
    if (__any(grow_)) { \
      float scl_[4]; \
      _Pragma("unroll") for (int r_ = 0; r_ < 4; ++r_) { \
        float mn_ = fmaxf(mrow[r_], mx_[r_]); \
        scl_[r_] = __expf(mrow[r_] - mn_); \
        mrow[r_] = mn_; \
        float ls_ = 0.0f; \
        _Pragma("unroll") for (int jt_ = 0; jt_ < 4; ++jt_) { \
          sc[jt_][r_] = __expf(sc[jt_][r_] - mn_); ls_ += sc[jt_][r_]; } \
        lrow[r_] = lrow[r_] * scl_[r_] + ls_; \
      } \
      _Pragma("unroll") for (int g_ = 0; g_ < 8; ++g_) \
        _Pragma("unroll") for (int r_ = 0; r_ < 4; ++r_) acc[g_][r_] *= scl_[r_]; \
    } else { \
      _Pragma("unroll") for (int r_ = 0; r_ < 4; ++r_) { \
        float ls_ = 0.0f; \
        _Pragma("unroll") for (int jt_ = 0; jt_ < 4; ++jt_) { \
          sc[jt_][r_] = __expf(sc[jt_][r_] - mrow[r_]); ls_ += sc[jt_][r_]; } \
        lrow[r_] += ls_; \
      } \
    } \
    /* P -> fp16, slot-XOR swizzled [16][64]: slot' = slot ^ (row&7) */ \
    _Pragma("unroll") for (int jt_ = 0; jt_ < 4; ++jt_) \
      _Pragma("unroll") for (int r_ = 0; r_ < 4; ++r_) { \
        int row_ = hi * 4 + r_; \
        int slot_ = (jt_ * 2 + (lr >> 3)) ^ (row_ & 7); \
        Pw[row_ * 64 + slot_ * 8 + (lr & 7)] = (half_t)sc[jt_][r_]; \
      } \
    half8 pf0_ = *(const half8*)&Pw[lr * 64 + ((hi ^ (lr & 7)) << 3)]; \
    half8 pf1_ = *(const half8*)&Pw[lr * 64 + (((4 + hi) ^ (lr & 7)) << 3)]; \
    __builtin_amdgcn_s_setprio(1); \
    _Pragma("unroll") for (int g_ = 0; g_ < 8; ++g_) { \
      int vrow_ = g_ * 16 + lr; \
      { int c0_ = (hi ^ vrow_) & 7; \
        half8 vf_ = *(const half8*)&Vlds[BUF][vrow_ * 64 + c0_ * 8]; \
        acc[g_] = __builtin_amdgcn_mfma_f32_16x16x32_f16(pf0_, vf_, acc[g_], 0, 0, 0); } \
      { int c1_ = ((4 + hi) ^ vrow_) & 7; \
        half8 vf_ = *(const half8*)&Vlds[BUF][vrow_ * 64 + c1_ * 8]; \
        acc[g_] = __builtin_amdgcn_mfma_f32_16x16x32_f16(pf1_, vf_, acc[g_], 0, 0, 0); } \
    } \
    __builtin_amdgcn_s_setprio(0); }

#define TILE_SYNC() { asm volatile("s_waitcnt vmcnt(0)" ::: "memory"); \
                      __builtin_amdgcn_s_barrier(); __builtin_amdgcn_sched_barrier(0); }

  const int nt = 2 * qb + 2;
  STAGE_KV(0, 0);
  TILE_SYNC();

  int t = 0;
  for (; t + 2 <= nt; t += 2) {
    STAGE_KV((t + 1) * 64, 1);
    COMPUTE(t, 0);
    TILE_SYNC();
    if (t + 2 < nt) { STAGE_KV((t + 2) * 64, 0); }
    COMPUTE(t + 1, 1);
    TILE_SYNC();
  }
  if (t < nt) { COMPUTE(t, 0); }   // (nt even; kept for safety)

#undef STAGE_KV
#undef COMPUTE
#undef TILE_SYNC

  float linv[4];
#pragma unroll
  for (int r = 0; r < 4; ++r) {
    float l = lrow[r];
#pragma unroll
    for (int off = 1; off < 16; off <<= 1) l += __shfl_xor(l, off, 64);
    linv[r] = 1.0f / l;
  }
#pragma unroll
  for (int g = 0; g < 8; ++g)
#pragma unroll
    for (int r = 0; r < 4; ++r) {
      int row = qrow + hi * 4 + r;
      int col = h * HD + g * 16 + lr;
      Ob[(size_t)row * HID + col] = (half_t)(acc[g][r] * linv[r]);
    }
}

// ---------------- launch ----------------
extern "C" void kernel_launch(void* const* d_in, const int* in_sizes, int n_in,
                              void* d_out, int out_size, void* d_ws, size_t ws_size,
                              hipStream_t stream) {
  const float* hs = (const float*)d_in[0];
  const float* Wq = (const float*)d_in[1];
  const float* Wk = (const float*)d_in[2];
  const float* Wv = (const float*)d_in[3];
  const float* Wo = (const float*)d_in[4];
  float* out = (float*)d_out;

  char* ws = (char*)d_ws;
  half_t* Xh    = (half_t*)(ws + 0);           // 16 MB (dead after gemm1)
  half_t* Vt    = (half_t*)(ws + 0);           // 4 MB, reuses Xh region
  half_t* Wqkvh = (half_t*)(ws + 16777216);    // 48 MB [6144][4096]
  half_t* Woh   = (half_t*)(ws + 67108864);    // 32 MB
  half_t* QKV   = (half_t*)(ws + 100663296);   // 24 MB [2048][6144]
  half_t* attnh = (half_t*)(ws + 125829120);   // 16 MB [2048][4096]
  float*  cs    = (float*)(ws + 142606336);    // 1 MB cos|sin tables
  if (ws_size < 143654912ull) return;

  cast_all_k<<<49152, 256, 0, stream>>>(hs, Wq, Wk, Wv, Wo, Xh, Wqkvh, Woh);
  rope_tables_k<<<512, 256, 0, stream>>>(cs);

  gemm8p_k<256, 192, 1><<<256, 512, 0, stream>>>(Xh, Wqkvh, (void*)QKV, 2048, 6144, 4096);
  rope_vt_k<<<21504, 256, 0, stream>>>(QKV, cs, Vt);
  attn_k<<<512, 512, 0, stream>>>(QKV, Vt, attnh);
  gemm8p_k<128, 256, 0><<<256, 512, 0, stream>>>(attnh, Woh, (void*)out, 2048, 4096, 4096);
}

// Round 13
// 312.850 us; speedup vs baseline: 1.6946x; 1.0711x over previous
//
#include <hip/hip_runtime.h>
#include <stdint.h>

#define T_SEQ   2048
#define HID     4096
#define NH      32
#define NKV     8
#define HD      128
#define QCOLS   6144
#define QK_SCALE 0.08838834764831845f  // 1/sqrt(128)

typedef _Float16 half_t;
typedef _Float16 half8 __attribute__((ext_vector_type(8)));
typedef _Float16 half4v __attribute__((ext_vector_type(4)));
typedef float    f32x4 __attribute__((ext_vector_type(4)));

typedef __attribute__((address_space(1))) const void cg_void;
typedef __attribute__((address_space(3))) void lds_void;

// ---------------- cast fp32 -> fp16 for X only (weights read fp32 by GEMM) --
__global__ __launch_bounds__(256) void cast_x_k(const float* __restrict__ X,
                                                half_t* __restrict__ Xh) {
  int i = blockIdx.x * 256 + threadIdx.x;   // float4 index, total 2097152
  f32x4 v = *(const f32x4*)(X + (size_t)i * 4);
  half4v o;
  o[0] = (half_t)v[0]; o[1] = (half_t)v[1]; o[2] = (half_t)v[2]; o[3] = (half_t)v[3];
  *(half4v*)(Xh + (size_t)i * 4) = o;
}

// ---------------- RoPE cos/sin tables ----------------
__global__ __launch_bounds__(256) void rope_tables_k(float* __restrict__ cs) {
  int idx = blockIdx.x * 256 + threadIdx.x;  // 2048*64
  int t = idx >> 6, i = idx & 63;
  float inv = expf(-(float)i * 0.14391156831212787f);
  float a = (float)t * inv;
  cs[idx] = cosf(a);
  cs[131072 + idx] = sinf(a);
}

// ---------- fused: RoPE apply (blocks < 20480) + V transpose (rest) ----------
__global__ __launch_bounds__(256) void rope_vt_k(half_t* __restrict__ QKV,
                                                 const float* __restrict__ cs,
                                                 half_t* __restrict__ Vt) {
  if (blockIdx.x < 20480) {
    int idx = blockIdx.x * 256 + threadIdx.x;  // 2048*40*64
    int i = idx & 63;
    int rem = idx >> 6;
    int head = rem % 40;
    int t = rem / 40;
    int colbase = (head < 32) ? head * HD : HID + (head - 32) * HD;
    size_t base = (size_t)t * QCOLS + colbase;
    float c = cs[t * 64 + i], s = cs[131072 + t * 64 + i];
    float x1 = (float)QKV[base + i];
    float x2 = (float)QKV[base + 64 + i];
    float o1 = x1 * c - x2 * s;
    float o2 = x1 * s + x2 * c;
    if (head < 32) { o1 *= QK_SCALE; o2 *= QK_SCALE; }
    QKV[base + i]      = (half_t)o1;
    QKV[base + 64 + i] = (half_t)o2;
  } else {
    int idx = (blockIdx.x - 20480) * 256 + threadIdx.x;   // 8*128*256 = 262144
    int d  = idx & 127;
    int ts = (idx >> 7) & 255;
    int kh = idx >> 15;
    half8 o;
#pragma unroll
    for (int i = 0; i < 8; ++i)
      o[i] = QKV[(size_t)(ts * 8 + i) * QCOLS + HID + NKV * HD + kh * HD + d];
    *(half8*)&Vt[(size_t)kh * (HD * T_SEQ) + (size_t)d * T_SEQ + ts * 8] = o;
  }
}

// ---------------- fp16 GEMM (R3 sync skeleton), B read directly as fp32 ----
// C[M][N] = A[M][K] * B[N][K]^T.  A: fp16 via global_load_lds (pre-swizzled
// source). B: fp32 rows from Bq/Bk/Bv (concat split at 4096/5120), loaded to
// regs at ph1 (per-thread base pointers precomputed once -- row & swizzle are
// K-invariant), converted + ds_write'd at ph3 inside the existing drain
// region. Sync structure identical to the verified R3/R8 kernel.
template <int BM, int BN, int OUT_HALF>
__global__ __launch_bounds__(512, 2) void gemm8p_k(const half_t* __restrict__ A,
                                                   const float* __restrict__ Bq,
                                                   const float* __restrict__ Bk,
                                                   const float* __restrict__ Bv,
                                                   void* __restrict__ Cout,
                                                   int M, int N, int K) {
  constexpr int MF = BM / 32;   // per-wave m fragments
  constexpr int NF = BN / 64;   // per-wave n fragments
  constexpr int MH = MF / 2;    // m frags per phase
  constexpr int LA = BM / 64;   // A staging loads/thread per tile
  constexpr int LB = BN / 64;   // B loads/thread per tile
  __shared__ half_t Al[2][BM * 64];
  __shared__ half_t Bl[2][BN * 64];

  const int nbm = M / BM;
  const int nwg = nbm * (N / BN);     // 256 for both instantiations
  const int bid = blockIdx.x;
  const int swz = (bid & 7) * (nwg >> 3) + (bid >> 3);  // bijective XCD swizzle
  const int brow = (swz % nbm) * BM;
  const int bcol = (swz / nbm) * BN;
  const int tid = threadIdx.x;
  const int lane = tid & 63, wid = tid >> 6;
  const int wr = wid >> 2, wc = wid & 3;
  const int lr = lane & 15, hi = lane >> 4;
  const int wrow = wr * (MF * 16), wcol = wc * (NF * 16);

  const half_t* Ab = A + (size_t)brow * K;

  // per-thread B source pointers (row + swizzle constant across K-tiles)
  const float* bp[LB];
#pragma unroll
  for (int l = 0; l < LB; ++l) {
    int c = l * 512 + tid, r = c >> 3, s = c & 7;
    int row = bcol + r;
    const float* src = (row < 4096) ? (Bq + (size_t)row * K)
                     : (row < 5120) ? (Bk + (size_t)(row - 4096) * K)
                                    : (Bv + (size_t)(row - 5120) * K);
    bp[l] = src + ((s ^ (r & 7)) * 8);
  }

  f32x4 acc[MF][NF] = {};
  half8 afr[MH], bfr[NF];
  f32x4 breg[LB][2];

#define STAGE_A(l, k0, buf) { \
    int c_ = (l) * 512 + tid; int r_ = c_ >> 3, s_ = c_ & 7; \
    __builtin_amdgcn_global_load_lds( \
      (cg_void*)(Ab + (size_t)r_ * K + (k0) + ((s_ ^ (r_ & 7)) * 8)), \
      (lds_void*)(&Al[buf][((l) * 512 + wid * 64) * 8]), 16, 0, 0); }
#define LOAD_B_ALL(k0) { \
    _Pragma("unroll") for (int l_ = 0; l_ < LB; ++l_) { \
      breg[l_][0] = *(const f32x4*)(bp[l_] + (k0)); \
      breg[l_][1] = *(const f32x4*)(bp[l_] + (k0) + 4); } }
#define WRITE_B_ALL(buf) { \
    _Pragma("unroll") for (int l_ = 0; l_ < LB; ++l_) { \
      half8 h_; \
      _Pragma("unroll") for (int e_ = 0; e_ < 4; ++e_) { \
        h_[e_] = (half_t)breg[l_][0][e_]; h_[4 + e_] = (half_t)breg[l_][1][e_]; } \
      *(half8*)&Bl[buf][((l_) * 512 + tid) * 8] = h_; } }
#define RD_A(i, mh, kk, buf) { \
    int row_ = wrow + ((mh) * MH + (i)) * 16 + lr; int ks_ = (kk) * 4 + hi; \
    afr[i] = *(const half8*)&Al[buf][row_ * 64 + ((ks_ ^ (row_ & 7)) * 8)]; }
#define RD_B(n, kk, buf) { \
    int row_ = wcol + (n) * 16 + lr; int ks_ = (kk) * 4 + hi; \
    bfr[n] = *(const half8*)&Bl[buf][row_ * 64 + ((ks_ ^ (row_ & 7)) * 8)]; }
#define MFMA_PH(mh) { \
    __builtin_amdgcn_s_setprio(1); \
    _Pragma("unroll") for (int i_ = 0; i_ < MH; ++i_) \
      _Pragma("unroll") for (int n_ = 0; n_ < NF; ++n_) \
        acc[(mh) * MH + i_][n_] = __builtin_amdgcn_mfma_f32_16x16x32_f16( \
            afr[i_], bfr[n_], acc[(mh) * MH + i_][n_], 0, 0, 0); \
    __builtin_amdgcn_s_setprio(0); }

#define DO_TILE(T, BUF) { \
    const int kn_ = ((T) + 1) * 64; const bool pf_ = ((T) + 1) < NT; \
    if (pf_) { _Pragma("unroll") for (int l_ = 0; l_ < LA; ++l_) STAGE_A(l_, kn_, (BUF) ^ 1); } \
    _Pragma("unroll") for (int n_ = 0; n_ < NF; ++n_) RD_B(n_, 0, BUF); \
    _Pragma("unroll") for (int i_ = 0; i_ < MH; ++i_) RD_A(i_, 0, 0, BUF); \
    MFMA_PH(0); \
    __builtin_amdgcn_s_barrier(); __builtin_amdgcn_sched_barrier(0); \
    if (pf_) { LOAD_B_ALL(kn_); } \
    _Pragma("unroll") for (int i_ = 0; i_ < MH; ++i_) RD_A(i_, 1, 0, BUF); \
    MFMA_PH(1); \
    __builtin_amdgcn_s_barrier(); __builtin_amdgcn_sched_barrier(0); \
    _Pragma("unroll") for (int n_ = 0; n_ < NF; ++n_) RD_B(n_, 1, BUF); \
    _Pragma("unroll") for (int i_ = 0; i_ < MH; ++i_) RD_A(i_, 1, 1, BUF); \
    MFMA_PH(1); \
    __builtin_amdgcn_s_barrier(); __builtin_amdgcn_sched_barrier(0); \
    _Pragma("unroll") for (int i_ = 0; i_ < MH; ++i_) RD_A(i_, 0, 1, BUF); \
    MFMA_PH(0); \
    if (pf_) { WRITE_B_ALL((BUF) ^ 1); } \
    asm volatile("s_waitcnt vmcnt(0)" ::: "memory"); \
    __syncthreads(); }

  const int NT = K / 64;
  // prologue: stage tile 0 (A via gload_lds, B via reg+cvt), drain, sync
#pragma unroll
  for (int l_ = 0; l_ < LA; ++l_) STAGE_A(l_, 0, 0);
  LOAD_B_ALL(0);
  WRITE_B_ALL(0);
  asm volatile("s_waitcnt vmcnt(0)" ::: "memory");
  __syncthreads();

  for (int t = 0; t < NT; t += 2) {
    DO_TILE(t, 0);
    DO_TILE(t + 1, 1);
  }

#undef STAGE_A
#undef LOAD_B_ALL
#undef WRITE_B_ALL
#undef RD_A
#undef RD_B
#undef MFMA_PH
#undef DO_TILE

#pragma unroll
  for (int m = 0; m < MF; ++m)
#pragma unroll
    for (int n = 0; n < NF; ++n)
#pragma unroll
      for (int r = 0; r < 4; ++r) {
        int row = brow + wrow + m * 16 + hi * 4 + r;
        int col = bcol + wcol + n * 16 + lr;
        float v = acc[m][n][r];
        if (OUT_HALF) ((half_t*)Cout)[(size_t)row * N + col] = (half_t)v;
        else          ((float*)Cout)[(size_t)row * N + col] = v;
      }
}

// ---------------- fused causal GQA flash attention (R10-verified) ----------
// 4 waves, QBLK=64, 2-phase prefetch, setprio on MFMA clusters, defer-max,
// lane-partial l. Grid 1024 = 32 qb (longest first) x 32 heads.
__global__ __launch_bounds__(256, 2) void attn_k(const half_t* __restrict__ QKV,
                                                 const half_t* __restrict__ Vt,
                                                 half_t* __restrict__ Ob) {
  const int bid = blockIdx.x;
  const int qb = 31 - (bid >> 5);   // longest blocks dispatch first
  const int h  = bid & 31;
  const int kh = h >> 2;
  const int tid = threadIdx.x;
  const int lane = tid & 63;
  const int w = tid >> 6;
  const int lr = lane & 15, hi = lane >> 4;
  const int qrow = qb * 64 + w * 16;

  __shared__ half_t Klds[2][64 * 128];   // [kv][128] swizzled-linear
  __shared__ half_t Vlds[2][128 * 64];   // [d][kv]   swizzled-linear
  __shared__ half_t Plds[4 * 16 * 72];   // per-wave P, padded rows

  const half_t* Qp  = QKV + h * HD;
  const half_t* Kp  = QKV + HID + kh * HD;
  const half_t* Vtp = Vt + (size_t)kh * (HD * T_SEQ);

  half8 qf[4];
#pragma unroll
  for (int kk = 0; kk < 4; ++kk)
    qf[kk] = *(const half8*)&Qp[(size_t)(qrow + lr) * QCOLS + kk * 32 + hi * 8];

  f32x4 acc[8] = {};
  float mrow[4], lrow[4];
#pragma unroll
  for (int r = 0; r < 4; ++r) { mrow[r] = -1e30f; lrow[r] = 0.0f; }

  half_t* Pw = &Plds[w * (16 * 72)];

#define STAGE_KV(kv0, buf) { \
    _Pragma("unroll") for (int c_ = 0; c_ < 4; ++c_) { \
      int chunk_ = c_ * 256 + tid; \
      int r_ = chunk_ >> 4, s_ = chunk_ & 15; \
      int cc_ = (s_ & 8) | ((s_ ^ r_) & 7); \
      __builtin_amdgcn_global_load_lds( \
          (cg_void*)(Kp + (size_t)((kv0) + r_) * QCOLS + cc_ * 8), \
          (lds_void*)(&Klds[buf][(c_ * 256 + w * 64) * 8]), 16, 0, 0); } \
    _Pragma("unroll") for (int c_ = 0; c_ < 4; ++c_) { \
      int chunk_ = c_ * 256 + tid; \
      int r_ = chunk_ >> 3, s_ = chunk_ & 7; \
      int cc_ = (s_ ^ r_) & 7; \
      __builtin_amdgcn_global_load_lds( \
          (cg_void*)(Vtp + (size_t)r_ * T_SEQ + (kv0) + cc_ * 8), \
          (lds_void*)(&Vlds[buf][(c_ * 256 + w * 64) * 8]), 16, 0, 0); } }

#define COMPUTE(T, BUF) { \
    const int kv0_ = (T) * 64; \
    f32x4 sc[4] = {}; \
    __builtin_amdgcn_s_setprio(1); \
    _Pragma("unroll") for (int jt_ = 0; jt_ < 4; ++jt_) \
      _Pragma("unroll") for (int kk_ = 0; kk_ < 4; ++kk_) { \
        int srow_ = jt_ * 16 + lr; \
        int sl_ = kk_ * 4 + hi; \
        int c_ = (sl_ & 8) | ((sl_ ^ srow_) & 7); \
        half8 kf_ = *(const half8*)&Klds[BUF][srow_ * 128 + c_ * 8]; \
        sc[jt_] = __builtin_amdgcn_mfma_f32_16x16x32_f16(qf[kk_], kf_, sc[jt_], 0, 0, 0); \
      } \
    __builtin_amdgcn_s_setprio(0); \
    if ((T) == qb) { \
      _Pragma("unroll") for (int jt_ = 0; jt_ < 4; ++jt_) \
        _Pragma("unroll") for (int r_ = 0; r_ < 4; ++r_) { \
          int ig_ = qrow + hi * 4 + r_; \
          int jg_ = kv0_ + jt_ * 16 + lr; \
          if (jg_ > ig_) sc[jt_][r_] = -1e30f; \
        } \
    } \
    float mx_[4]; \
    _Pragma("unroll") for (int r_ = 0; r_ < 4; ++r_) \
      mx_[r_] = fmaxf(fmaxf(sc[0][r_], sc[1][r_]), fmaxf(sc[2][r_], sc[3][r_])); \
    _Pragma("unroll") for (int off_ = 1; off_ < 16; off_ <<= 1) \
      _Pragma("unroll") for (int r_ = 0; r_ < 4; ++r_) \
        mx_[r_] = fmaxf(mx_[r_], __shfl_xor(mx_[r_], off_, 64)); \
    bool grow_ = false; \
    _Pragma("unroll") for (int r_ = 0; r_ < 4; ++r_) grow_ = grow_ || (mx_[r_] > mrow[r_]); \
    if (__any(grow_)) { \
      float scl_[4]; \
      _Pragma("unroll") for (int r_ = 0; r_ < 4; ++r_) { \
        float mn_ = fmaxf(mrow[r_], mx_[r_]); \
        scl_[r_] = __expf(mrow[r_] - mn_); \
        mrow[r_] = mn_; \
        float ls_ = 0.0f; \
        _Pragma("unroll") for (int jt_ = 0; jt_ < 4; ++jt_) { \
          sc[jt_][r_] = __expf(sc[jt_][r_] - mn_); ls_ += sc[jt_][r_]; } \
        lrow[r_] = lrow[r_] * scl_[r_] + ls_; \
      } \
      _Pragma("unroll") for (int g_ = 0; g_ < 8; ++g_) \
        _Pragma("unroll") for (int r_ = 0; r_ < 4; ++r_) acc[g_][r_] *= scl_[r_]; \
    } else { \
      _Pragma("unroll") for (int r_ = 0; r_ < 4; ++r_) { \
        float ls_ = 0.0f; \
        _Pragma("unroll") for (int jt_ = 0; jt_ < 4; ++jt_) { \
          sc[jt_][r_] = __expf(sc[jt_][r_] - mrow[r_]); ls_ += sc[jt_][r_]; } \
        lrow[r_] += ls_; \
      } \
    } \
    _Pragma("unroll") for (int jt_ = 0; jt_ < 4; ++jt_) \
      _Pragma("unroll") for (int r_ = 0; r_ < 4; ++r_) \
        Pw[(hi * 4 + r_) * 72 + jt_ * 16 + lr] = (half_t)sc[jt_][r_]; \
    half8 pf0_ = *(const half8*)&Pw[lr * 72 + hi * 8]; \
    half8 pf1_ = *(const half8*)&Pw[lr * 72 + 32 + hi * 8]; \
    __builtin_amdgcn_s_setprio(1); \
    _Pragma("unroll") for (int g_ = 0; g_ < 8; ++g_) { \
      int vrow_ = g_ * 16 + lr; \
      { int c0_ = (hi ^ vrow_) & 7; \
        half8 vf_ = *(const half8*)&Vlds[BUF][vrow_ * 64 + c0_ * 8]; \
        acc[g_] = __builtin_amdgcn_mfma_f32_16x16x32_f16(pf0_, vf_, acc[g_], 0, 0, 0); } \
      { int c1_ = ((4 + hi) ^ vrow_) & 7; \
        half8 vf_ = *(const half8*)&Vlds[BUF][vrow_ * 64 + c1_ * 8]; \
        acc[g_] = __builtin_amdgcn_mfma_f32_16x16x32_f16(pf1_, vf_, acc[g_], 0, 0, 0); } \
    } \
    __builtin_amdgcn_s_setprio(0); }

#define TILE_SYNC() { asm volatile("s_waitcnt vmcnt(0)" ::: "memory"); \
                      __builtin_amdgcn_s_barrier(); __builtin_amdgcn_sched_barrier(0); }

  const int nt = qb + 1;
  STAGE_KV(0, 0);
  TILE_SYNC();

  int t = 0;
  for (; t + 2 <= nt; t += 2) {
    STAGE_KV((t + 1) * 64, 1);
    COMPUTE(t, 0);
    TILE_SYNC();
    if (t + 2 < nt) { STAGE_KV((t + 2) * 64, 0); }
    COMPUTE(t + 1, 1);
    TILE_SYNC();
  }
  if (t < nt) { COMPUTE(t, 0); }

#undef STAGE_KV
#undef COMPUTE
#undef TILE_SYNC

  float linv[4];
#pragma unroll
  for (int r = 0; r < 4; ++r) {
    float l = lrow[r];
#pragma unroll
    for (int off = 1; off < 16; off <<= 1) l += __shfl_xor(l, off, 64);
    linv[r] = 1.0f / l;
  }
#pragma unroll
  for (int g = 0; g < 8; ++g)
#pragma unroll
    for (int r = 0; r < 4; ++r) {
      int row = qrow + hi * 4 + r;
      int col = h * HD + g * 16 + lr;
      Ob[(size_t)row * HID + col] = (half_t)(acc[g][r] * linv[r]);
    }
}

// ---------------- launch ----------------
extern "C" void kernel_launch(void* const* d_in, const int* in_sizes, int n_in,
                              void* d_out, int out_size, void* d_ws, size_t ws_size,
                              hipStream_t stream) {
  const float* hs = (const float*)d_in[0];
  const float* Wq = (const float*)d_in[1];
  const float* Wk = (const float*)d_in[2];
  const float* Wv = (const float*)d_in[3];
  const float* Wo = (const float*)d_in[4];
  float* out = (float*)d_out;

  char* ws = (char*)d_ws;
  half_t* Xh    = (half_t*)(ws + 0);           // 16 MB (dead after gemm1)
  half_t* Vt    = (half_t*)(ws + 0);           // 4 MB, reuses Xh region
  half_t* QKV   = (half_t*)(ws + 100663296);   // 24 MB [2048][6144]
  half_t* attnh = (half_t*)(ws + 125829120);   // 16 MB [2048][4096]
  float*  cs    = (float*)(ws + 142606336);    // 1 MB cos|sin tables
  if (ws_size < 143654912ull) return;

  cast_x_k<<<8192, 256, 0, stream>>>(hs, Xh);
  rope_tables_k<<<512, 256, 0, stream>>>(cs);

  gemm8p_k<256, 192, 1><<<256, 512, 0, stream>>>(Xh, Wq, Wk, Wv, (void*)QKV, 2048, 6144, 4096);
  rope_vt_k<<<21504, 256, 0, stream>>>(QKV, cs, Vt);
  attn_k<<<1024, 256, 0, stream>>>(QKV, Vt, attnh);
  gemm8p_k<256, 128, 0><<<256, 512, 0, stream>>>(attnh, Wo, Wo, Wo, (void*)out, 2048, 4096, 4096);
}